// Round 1
// baseline (17884.821 us; speedup 1.0000x reference)
//
#include <hip/hip_runtime.h>
#include <cstddef>

constexpr int B  = 48;
constexpr int L  = 192;
constexpr int T  = 193;    // L + 1
constexpr int KD = 1024;   // I == H
constexpr int G3 = 3072;   // 3*H
constexpr int V  = 8192;
constexpr int M  = T * B;  // 9264

// ---------------------------------------------------------------------------
// h0[b,:] = event_table[ids[b],:]
__global__ __launch_bounds__(256)
void init_h0(const float* __restrict__ et, const int* __restrict__ ids,
             float* __restrict__ h0) {
  int b = blockIdx.x;
  int id = ids[b];
  ((float4*)(h0 + (size_t)b * KD))[threadIdx.x] =
      ((const float4*)(et + (size_t)id * KD))[threadIdx.x];
}

// ---------------------------------------------------------------------------
// C[m,n] = sum_k A[m,k] * W[n,k] + bias[n]
// GATHER=1: A row m (m = t*B+b) is start (t==0) else user_table[seq[b,t-1]]
// OUTMODE=0: C row-major [M,Ndim]; OUTMODE=1: C[(b*T+t)*Ndim + n]
template<int GATHER, int OUTMODE>
__global__ __launch_bounds__(256)
void gemm128(const float* __restrict__ A, const float* __restrict__ W,
             const float* __restrict__ bias, float* __restrict__ C,
             int Ndim,
             const int* __restrict__ seq, const float* __restrict__ startv,
             const float* __restrict__ table) {
  __shared__ __align__(16) float a_s[16][132];
  __shared__ __align__(16) float w_s[16][132];
  const int tid = threadIdx.x;
  const int m0 = blockIdx.x * 128;
  const int n0 = blockIdx.y * 128;
  const int tm = tid >> 4, tn = tid & 15;

  float acc[8][8];
#pragma unroll
  for (int i = 0; i < 8; ++i)
#pragma unroll
    for (int j = 0; j < 8; ++j) acc[i][j] = 0.f;

  for (int kt = 0; kt < KD; kt += 16) {
    __syncthreads();
    // stage A tile (128 rows x 16 k), transposed into a_s[k][m]
#pragma unroll
    for (int i = 0; i < 2; ++i) {
      int f = tid + i * 256;
      int r = f >> 2, kq = f & 3;
      int m = m0 + r;
      float4 v = make_float4(0.f, 0.f, 0.f, 0.f);
      if (m < M) {
        const float* src;
        if (GATHER) {
          int t = m / B, b = m - t * B;
          src = (t == 0) ? startv : (table + (size_t)seq[b * L + (t - 1)] * KD);
        } else {
          src = A + (size_t)m * KD;
        }
        v = *(const float4*)(src + kt + kq * 4);
      }
      a_s[kq * 4 + 0][r] = v.x;
      a_s[kq * 4 + 1][r] = v.y;
      a_s[kq * 4 + 2][r] = v.z;
      a_s[kq * 4 + 3][r] = v.w;
    }
    // stage W tile (128 rows x 16 k) -> w_s[k][n]  (Ndim % 128 == 0)
#pragma unroll
    for (int i = 0; i < 2; ++i) {
      int f = tid + i * 256;
      int r = f >> 2, kq = f & 3;
      const float* src = W + (size_t)(n0 + r) * KD;
      float4 v = *(const float4*)(src + kt + kq * 4);
      w_s[kq * 4 + 0][r] = v.x;
      w_s[kq * 4 + 1][r] = v.y;
      w_s[kq * 4 + 2][r] = v.z;
      w_s[kq * 4 + 3][r] = v.w;
    }
    __syncthreads();
#pragma unroll
    for (int kk = 0; kk < 16; ++kk) {
      float4 a0 = *(const float4*)&a_s[kk][tm * 8];
      float4 a1 = *(const float4*)&a_s[kk][tm * 8 + 4];
      float4 b0 = *(const float4*)&w_s[kk][tn * 8];
      float4 b1 = *(const float4*)&w_s[kk][tn * 8 + 4];
      float av[8] = {a0.x, a0.y, a0.z, a0.w, a1.x, a1.y, a1.z, a1.w};
      float bv[8] = {b0.x, b0.y, b0.z, b0.w, b1.x, b1.y, b1.z, b1.w};
#pragma unroll
      for (int i = 0; i < 8; ++i)
#pragma unroll
        for (int j = 0; j < 8; ++j)
          acc[i][j] = fmaf(av[i], bv[j], acc[i][j]);
    }
  }

#pragma unroll
  for (int i = 0; i < 8; ++i) {
    int m = m0 + tm * 8 + i;
    if (m >= M) continue;
    size_t rowoff;
    if (OUTMODE == 0) {
      rowoff = (size_t)m * (size_t)Ndim;
    } else {
      int t = m / B, b = m - t * B;
      rowoff = ((size_t)b * T + t) * (size_t)Ndim;
    }
    float* dst = C + rowoff + n0 + tn * 8;
#pragma unroll
    for (int j = 0; j < 8; ++j) dst[j] = acc[i][j] + bias[n0 + tn * 8 + j];
  }
}

// ---------------------------------------------------------------------------
// One GRU step: h_y[b,c] from h_in, xp_t (= x@Wih^T + b_ih, [B,3H]), w_hh, b_hh
// Grid: (64 c-blocks of 16, 3 b-blocks of 16). Thread (bl,cl) computes 3 dots.
__global__ __launch_bounds__(256)
void gru_step(const float* __restrict__ xp_t, const float* __restrict__ w_hh,
              const float* __restrict__ b_hh, const float* __restrict__ h_in,
              float* __restrict__ h_y) {
  __shared__ __align__(16) float h_s[16][132];
  __shared__ __align__(16) float w_s[48][132];
  const int tid = threadIdx.x;
  const int c0 = blockIdx.x * 16;
  const int b0 = blockIdx.y * 16;
  const int bl = tid >> 4, cl = tid & 15;

  float ar = 0.f, az = 0.f, an = 0.f;
  for (int kt = 0; kt < KD; kt += 128) {
    __syncthreads();
#pragma unroll
    for (int i = 0; i < 2; ++i) {           // h tile: 16x128
      int f = tid + i * 256;
      int r = f >> 5, c4 = f & 31;
      float4 v = *(const float4*)(h_in + (size_t)(b0 + r) * KD + kt + c4 * 4);
      *(float4*)&h_s[r][c4 * 4] = v;
    }
#pragma unroll
    for (int i = 0; i < 6; ++i) {           // w tile: 48 rows (16c x 3 gates) x128
      int f = tid + i * 256;
      int r = f >> 5, c4 = f & 31;
      int g = r >> 4, c = c0 + (r & 15);
      float4 v = *(const float4*)(w_hh + (size_t)(g * KD + c) * KD + kt + c4 * 4);
      *(float4*)&w_s[r][c4 * 4] = v;
    }
    __syncthreads();
#pragma unroll
    for (int q = 0; q < 32; ++q) {
      float4 h4 = *(const float4*)&h_s[bl][q * 4];
      float4 wr = *(const float4*)&w_s[cl][q * 4];
      float4 wz = *(const float4*)&w_s[16 + cl][q * 4];
      float4 wn = *(const float4*)&w_s[32 + cl][q * 4];
      ar = fmaf(h4.x, wr.x, ar); ar = fmaf(h4.y, wr.y, ar);
      ar = fmaf(h4.z, wr.z, ar); ar = fmaf(h4.w, wr.w, ar);
      az = fmaf(h4.x, wz.x, az); az = fmaf(h4.y, wz.y, az);
      az = fmaf(h4.z, wz.z, az); az = fmaf(h4.w, wz.w, az);
      an = fmaf(h4.x, wn.x, an); an = fmaf(h4.y, wn.y, an);
      an = fmaf(h4.z, wn.z, an); an = fmaf(h4.w, wn.w, an);
    }
  }
  int b = b0 + bl, c = c0 + cl;
  float hr = ar + b_hh[c];
  float hz = az + b_hh[KD + c];
  float hn = an + b_hh[2 * KD + c];
  const float* xrow = xp_t + (size_t)b * G3;
  float xr = xrow[c], xz = xrow[KD + c], xn = xrow[2 * KD + c];
  float r = 1.f / (1.f + expf(-(xr + hr)));
  float z = 1.f / (1.f + expf(-(xz + hz)));
  float n = tanhf(xn + r * hn);
  float hold = h_in[(size_t)b * KD + c];
  h_y[(size_t)b * KD + c] = (1.f - z) * n + z * hold;
}

// ---------------------------------------------------------------------------
// In-place masked softmax over V for row (b,t). For t < L-1 only vocab ids in
// sequence[b, t:] stay; others get -1e30 (reference adds log(1e-45) ~ -103 ->
// probs ~1e-45, indistinguishable from 0 at fp32 tolerance).
__global__ __launch_bounds__(256)
void softmax_mask(float* __restrict__ out, const int* __restrict__ seq) {
  const int t = blockIdx.x, b = blockIdx.y;
  float* row = out + ((size_t)b * T + t) * V;
  __shared__ unsigned bits[V / 32];  // 256 words
  __shared__ float red[4];
  const int tid = threadIdx.x;
  const bool masked = (t < L - 1);
  if (masked) {
    bits[tid] = 0u;
    __syncthreads();
    int rem = L - t;  // 2..192 <= 256
    if (tid < rem) {
      int id = seq[b * L + t + tid];
      atomicOr(&bits[id >> 5], 1u << (id & 31));
    }
  }
  __syncthreads();

  float4 x[8];
  float mx = -3.0e38f;
#pragma unroll
  for (int j = 0; j < 8; ++j) {
    float4 v = ((const float4*)row)[j * 256 + tid];
    if (masked) {
      int vb = (j * 256 + tid) * 4;
      unsigned wrd = bits[vb >> 5];
      int sh = vb & 31;
      if (!((wrd >> (sh + 0)) & 1u)) v.x = -1.0e30f;
      if (!((wrd >> (sh + 1)) & 1u)) v.y = -1.0e30f;
      if (!((wrd >> (sh + 2)) & 1u)) v.z = -1.0e30f;
      if (!((wrd >> (sh + 3)) & 1u)) v.w = -1.0e30f;
    }
    x[j] = v;
    mx = fmaxf(mx, fmaxf(fmaxf(v.x, v.y), fmaxf(v.z, v.w)));
  }
#pragma unroll
  for (int off = 32; off > 0; off >>= 1) mx = fmaxf(mx, __shfl_xor(mx, off));
  int wv = tid >> 6;
  if ((tid & 63) == 0) red[wv] = mx;
  __syncthreads();
  mx = fmaxf(fmaxf(red[0], red[1]), fmaxf(red[2], red[3]));

  float s = 0.f;
#pragma unroll
  for (int j = 0; j < 8; ++j) {
    x[j].x = expf(x[j].x - mx); x[j].y = expf(x[j].y - mx);
    x[j].z = expf(x[j].z - mx); x[j].w = expf(x[j].w - mx);
    s += x[j].x + x[j].y + x[j].z + x[j].w;
  }
#pragma unroll
  for (int off = 32; off > 0; off >>= 1) s += __shfl_xor(s, off);
  __syncthreads();  // red[] reuse
  if ((tid & 63) == 0) red[wv] = s;
  __syncthreads();
  s = red[0] + red[1] + red[2] + red[3];
  float inv = 1.f / s;
#pragma unroll
  for (int j = 0; j < 8; ++j) {
    float4 v = make_float4(x[j].x * inv, x[j].y * inv, x[j].z * inv, x[j].w * inv);
    ((float4*)row)[j * 256 + tid] = v;
  }
}

// ---------------------------------------------------------------------------
extern "C" void kernel_launch(void* const* d_in, const int* in_sizes, int n_in,
                              void* d_out, int out_size, void* d_ws, size_t ws_size,
                              hipStream_t stream) {
  const float* event_table = (const float*)d_in[0];
  const float* user_table  = (const float*)d_in[1];
  const float* startv      = (const float*)d_in[2];
  const float* w_ih0 = (const float*)d_in[3];
  const float* w_hh0 = (const float*)d_in[4];
  const float* b_ih0 = (const float*)d_in[5];
  const float* b_hh0 = (const float*)d_in[6];
  const float* w_ih1 = (const float*)d_in[7];
  const float* w_hh1 = (const float*)d_in[8];
  const float* b_ih1 = (const float*)d_in[9];
  const float* b_hh1 = (const float*)d_in[10];
  const float* lin_w = (const float*)d_in[11];
  const float* lin_b = (const float*)d_in[12];
  const int*   ids   = (const int*)d_in[13];
  const int*   seq   = (const int*)d_in[14];
  float* out = (float*)d_out;

  // workspace: xp [M,3072] (shared by both layers), ys0/ys1 [M,1024], h0 [B,1024]
  float* xp  = (float*)d_ws;
  float* ys0 = xp  + (size_t)M * G3;
  float* ys1 = ys0 + (size_t)M * KD;
  float* h0  = ys1 + (size_t)M * KD;

  init_h0<<<dim3(B), 256, 0, stream>>>(event_table, ids, h0);

  // layer 0 input projection (with embedding gather)
  gemm128<1, 0><<<dim3((M + 127) / 128, G3 / 128), 256, 0, stream>>>(
      nullptr, w_ih0, b_ih0, xp, G3, seq, startv, user_table);

  // layer 0 scan
  for (int t = 0; t < T; ++t) {
    const float* hin = (t == 0) ? h0 : ys0 + (size_t)(t - 1) * B * KD;
    gru_step<<<dim3(64, 3), 256, 0, stream>>>(
        xp + (size_t)t * B * G3, w_hh0, b_hh0, hin, ys0 + (size_t)t * B * KD);
  }

  // layer 1 input projection
  gemm128<0, 0><<<dim3((M + 127) / 128, G3 / 128), 256, 0, stream>>>(
      ys0, w_ih1, b_ih1, xp, G3, nullptr, nullptr, nullptr);

  // layer 1 scan
  for (int t = 0; t < T; ++t) {
    const float* hin = (t == 0) ? h0 : ys1 + (size_t)(t - 1) * B * KD;
    gru_step<<<dim3(64, 3), 256, 0, stream>>>(
        xp + (size_t)t * B * G3, w_hh1, b_hh1, hin, ys1 + (size_t)t * B * KD);
  }

  // logits straight into d_out at [b][t][v]
  gemm128<0, 1><<<dim3((M + 127) / 128, V / 128), 256, 0, stream>>>(
      ys1, lin_w, lin_b, out, V, nullptr, nullptr, nullptr);

  // masked softmax in place
  softmax_mask<<<dim3(T, B), 256, 0, stream>>>(out, seq);
}

// Round 2
// 14812.384 us; speedup vs baseline: 1.2074x; 1.2074x over previous
//
#include <hip/hip_runtime.h>
#include <cstddef>
#include <cstdint>

constexpr int B  = 48;
constexpr int L  = 192;
constexpr int T  = 193;    // L + 1
constexpr int KD = 1024;   // I == H
constexpr int G3 = 3072;   // 3*H
constexpr int V  = 8192;
constexpr int M  = T * B;  // 9264

typedef float f32x4 __attribute__((ext_vector_type(4)));
typedef short s16x8 __attribute__((ext_vector_type(8)));
typedef unsigned short u16x8 __attribute__((ext_vector_type(8)));

__device__ inline unsigned short f2bf(float f) {
  unsigned u = __builtin_bit_cast(unsigned, f);
  u += 0x7fffu + ((u >> 16) & 1u);   // round-to-nearest-even
  return (unsigned short)(u >> 16);
}

// ---------------------------------------------------------------------------
__global__ __launch_bounds__(256)
void init_h0(const float* __restrict__ et, const int* __restrict__ ids,
             float* __restrict__ h0) {
  int b = blockIdx.x;
  int id = ids[b];
  ((float4*)(h0 + (size_t)b * KD))[threadIdx.x] =
      ((const float4*)(et + (size_t)id * KD))[threadIdx.x];
}

// fp32 -> bf16 (raw bits), 8 elems/thread
__global__ __launch_bounds__(256)
void cvt_bf16(const float* __restrict__ in, unsigned short* __restrict__ out,
              long long n) {
  long long i = ((long long)blockIdx.x * 256 + threadIdx.x) * 8;
  if (i + 8 > n) return;
  float4 v0 = *(const float4*)(in + i);
  float4 v1 = *(const float4*)(in + i + 4);
  u16x8 o;
  o[0] = f2bf(v0.x); o[1] = f2bf(v0.y); o[2] = f2bf(v0.z); o[3] = f2bf(v0.w);
  o[4] = f2bf(v1.x); o[5] = f2bf(v1.y); o[6] = f2bf(v1.z); o[7] = f2bf(v1.w);
  *(u16x8*)(out + i) = o;
}

// ---------------------------------------------------------------------------
// bf16 MFMA GEMM: C[m,n] = sum_k A[m,k]*W[n,k] + bias[n], fp32 out.
// A,W are bf16 (raw ushort). 128x128 tile, BK=32, 4 waves, 4x4 frags/wave.
// GATHER=1: A row m (= t*B+b) is start_bf (t==0) else table_bf[seq[b,t-1]].
// OUTMODE=0: C row-major [M,Ndim]; OUTMODE=1: C[(b*T+t)*Ndim + n].
template<int GATHER, int OUTMODE>
__global__ __launch_bounds__(256)
void gemm_bf16(const unsigned short* __restrict__ A,
               const unsigned short* __restrict__ W,
               const float* __restrict__ bias, float* __restrict__ C, int Ndim,
               const int* __restrict__ seq,
               const unsigned short* __restrict__ start_bf,
               const unsigned short* __restrict__ table_bf) {
  __shared__ __align__(16) unsigned short a_s[128 * 32];
  __shared__ __align__(16) unsigned short b_s[128 * 32];
  const int tid  = threadIdx.x;
  const int lane = tid & 63;
  const int wave = tid >> 6;
  const int m0 = blockIdx.x * 128;
  const int n0 = blockIdx.y * 128;
  const int wr = wave >> 1, wc = wave & 1;

  f32x4 acc[4][4];
#pragma unroll
  for (int i = 0; i < 4; ++i)
#pragma unroll
    for (int j = 0; j < 4; ++j) acc[i][j] = (f32x4){0.f, 0.f, 0.f, 0.f};

  const int lrow = lane & 15;   // row within 16-tile
  const int lkhi = lane >> 4;   // k-chunk 0..3 (8 bf16 each)

  for (int kt = 0; kt < KD; kt += 32) {
    __syncthreads();
    // stage A tile (128 rows x 32 k bf16 = 8KB): 2 x 16B per thread
#pragma unroll
    for (int j = 0; j < 2; ++j) {
      int flat = tid * 16 + j * 4096;       // byte offset in a_s
      int row = flat >> 6;                  // 64 B per row
      int cc = (flat >> 4) & 3;             // which 16B chunk of the row
      const unsigned short* src;
      if (GATHER) {
        int m = m0 + row; if (m >= M) m = 0;
        int t = m / B, b = m - t * B;
        const unsigned short* rowsrc =
            (t == 0) ? start_bf : (table_bf + (size_t)seq[b * L + t - 1] * KD);
        src = rowsrc + kt + cc * 8;
      } else {
        int m = m0 + row; if (m >= M) m = 0;
        src = A + (size_t)m * KD + kt + cc * 8;
      }
      *(int4*)((char*)a_s + flat) = *(const int4*)src;
    }
    // stage W tile (128 n-rows x 32 k)
#pragma unroll
    for (int j = 0; j < 2; ++j) {
      int flat = tid * 16 + j * 4096;
      int row = flat >> 6;
      int cc = (flat >> 4) & 3;
      const unsigned short* src = W + (size_t)(n0 + row) * KD + kt + cc * 8;
      *(int4*)((char*)b_s + flat) = *(const int4*)src;
    }
    __syncthreads();

    s16x8 af[4], bf[4];
#pragma unroll
    for (int i = 0; i < 4; ++i) {
      int arow = wr * 64 + i * 16 + lrow;
      af[i] = *(const s16x8*)((const char*)a_s + arow * 64 + lkhi * 16);
      int brow = wc * 64 + i * 16 + lrow;
      bf[i] = *(const s16x8*)((const char*)b_s + brow * 64 + lkhi * 16);
    }
#pragma unroll
    for (int i = 0; i < 4; ++i)
#pragma unroll
      for (int j = 0; j < 4; ++j)
        acc[i][j] = __builtin_amdgcn_mfma_f32_16x16x32_bf16(af[i], bf[j],
                                                            acc[i][j], 0, 0, 0);
  }

  // epilogue: C/D layout col = lane&15, row = (lane>>4)*4 + r
#pragma unroll
  for (int i = 0; i < 4; ++i) {
#pragma unroll
    for (int r = 0; r < 4; ++r) {
      int m = m0 + wr * 64 + i * 16 + (lane >> 4) * 4 + r;
      if (m >= M) continue;
      size_t rowoff;
      if (OUTMODE == 0) {
        rowoff = (size_t)m * (size_t)Ndim;
      } else {
        int t = m / B, b = m - t * B;
        rowoff = ((size_t)b * T + t) * (size_t)Ndim;
      }
#pragma unroll
      for (int j = 0; j < 4; ++j) {
        int n = n0 + wc * 64 + j * 16 + (lane & 15);
        C[rowoff + n] = acc[i][j][r] + bias[n];
      }
    }
  }
}

// ---------------------------------------------------------------------------
// One GRU step (fp32). Also writes bf16 copy of the new h for later GEMMs.
__global__ __launch_bounds__(256)
void gru_step(const float* __restrict__ xp_t, const float* __restrict__ w_hh,
              const float* __restrict__ b_hh, const float* __restrict__ h_in,
              float* __restrict__ h_y, unsigned short* __restrict__ y_bf) {
  __shared__ __align__(16) float h_s[16][132];
  __shared__ __align__(16) float w_s[48][132];
  const int tid = threadIdx.x;
  const int c0 = blockIdx.x * 16;
  const int b0 = blockIdx.y * 16;
  const int bl = tid >> 4, cl = tid & 15;

  float ar = 0.f, az = 0.f, an = 0.f;
  for (int kt = 0; kt < KD; kt += 128) {
    __syncthreads();
#pragma unroll
    for (int i = 0; i < 2; ++i) {
      int f = tid + i * 256;
      int r = f >> 5, c4 = f & 31;
      float4 v = *(const float4*)(h_in + (size_t)(b0 + r) * KD + kt + c4 * 4);
      *(float4*)&h_s[r][c4 * 4] = v;
    }
#pragma unroll
    for (int i = 0; i < 6; ++i) {
      int f = tid + i * 256;
      int r = f >> 5, c4 = f & 31;
      int g = r >> 4, c = c0 + (r & 15);
      float4 v = *(const float4*)(w_hh + (size_t)(g * KD + c) * KD + kt + c4 * 4);
      *(float4*)&w_s[r][c4 * 4] = v;
    }
    __syncthreads();
#pragma unroll
    for (int q = 0; q < 32; ++q) {
      float4 h4 = *(const float4*)&h_s[bl][q * 4];
      float4 wr = *(const float4*)&w_s[cl][q * 4];
      float4 wz = *(const float4*)&w_s[16 + cl][q * 4];
      float4 wn = *(const float4*)&w_s[32 + cl][q * 4];
      ar = fmaf(h4.x, wr.x, ar); ar = fmaf(h4.y, wr.y, ar);
      ar = fmaf(h4.z, wr.z, ar); ar = fmaf(h4.w, wr.w, ar);
      az = fmaf(h4.x, wz.x, az); az = fmaf(h4.y, wz.y, az);
      az = fmaf(h4.z, wz.z, az); az = fmaf(h4.w, wz.w, az);
      an = fmaf(h4.x, wn.x, an); an = fmaf(h4.y, wn.y, an);
      an = fmaf(h4.z, wn.z, an); an = fmaf(h4.w, wn.w, an);
    }
  }
  int b = b0 + bl, c = c0 + cl;
  float hr = ar + b_hh[c];
  float hz = az + b_hh[KD + c];
  float hn = an + b_hh[2 * KD + c];
  const float* xrow = xp_t + (size_t)b * G3;
  float xr = xrow[c], xz = xrow[KD + c], xn = xrow[2 * KD + c];
  float r = 1.f / (1.f + expf(-(xr + hr)));
  float z = 1.f / (1.f + expf(-(xz + hz)));
  float n = tanhf(xn + r * hn);
  float hold = h_in[(size_t)b * KD + c];
  float hnew = (1.f - z) * n + z * hold;
  h_y[(size_t)b * KD + c] = hnew;
  y_bf[(size_t)b * KD + c] = f2bf(hnew);
}

// ---------------------------------------------------------------------------
__global__ __launch_bounds__(256)
void softmax_mask(float* __restrict__ out, const int* __restrict__ seq) {
  const int t = blockIdx.x, b = blockIdx.y;
  float* row = out + ((size_t)b * T + t) * V;
  __shared__ unsigned bits[V / 32];
  __shared__ float red[4];
  const int tid = threadIdx.x;
  const bool masked = (t < L - 1);
  if (masked) {
    bits[tid] = 0u;
    __syncthreads();
    int rem = L - t;
    if (tid < rem) {
      int id = seq[b * L + t + tid];
      atomicOr(&bits[id >> 5], 1u << (id & 31));
    }
  }
  __syncthreads();

  float4 x[8];
  float mx = -3.0e38f;
#pragma unroll
  for (int j = 0; j < 8; ++j) {
    float4 v = ((const float4*)row)[j * 256 + tid];
    if (masked) {
      int vb = (j * 256 + tid) * 4;
      unsigned wrd = bits[vb >> 5];
      int sh = vb & 31;
      if (!((wrd >> (sh + 0)) & 1u)) v.x = -1.0e30f;
      if (!((wrd >> (sh + 1)) & 1u)) v.y = -1.0e30f;
      if (!((wrd >> (sh + 2)) & 1u)) v.z = -1.0e30f;
      if (!((wrd >> (sh + 3)) & 1u)) v.w = -1.0e30f;
    }
    x[j] = v;
    mx = fmaxf(mx, fmaxf(fmaxf(v.x, v.y), fmaxf(v.z, v.w)));
  }
#pragma unroll
  for (int off = 32; off > 0; off >>= 1) mx = fmaxf(mx, __shfl_xor(mx, off));
  int wv = tid >> 6;
  if ((tid & 63) == 0) red[wv] = mx;
  __syncthreads();
  mx = fmaxf(fmaxf(red[0], red[1]), fmaxf(red[2], red[3]));

  float s = 0.f;
#pragma unroll
  for (int j = 0; j < 8; ++j) {
    x[j].x = expf(x[j].x - mx); x[j].y = expf(x[j].y - mx);
    x[j].z = expf(x[j].z - mx); x[j].w = expf(x[j].w - mx);
    s += x[j].x + x[j].y + x[j].z + x[j].w;
  }
#pragma unroll
  for (int off = 32; off > 0; off >>= 1) s += __shfl_xor(s, off);
  __syncthreads();
  if ((tid & 63) == 0) red[wv] = s;
  __syncthreads();
  s = red[0] + red[1] + red[2] + red[3];
  float inv = 1.f / s;
#pragma unroll
  for (int j = 0; j < 8; ++j) {
    float4 v = make_float4(x[j].x * inv, x[j].y * inv, x[j].z * inv, x[j].w * inv);
    ((float4*)row)[j * 256 + tid] = v;
  }
}

// ---------------------------------------------------------------------------
extern "C" void kernel_launch(void* const* d_in, const int* in_sizes, int n_in,
                              void* d_out, int out_size, void* d_ws, size_t ws_size,
                              hipStream_t stream) {
  const float* event_table = (const float*)d_in[0];
  const float* user_table  = (const float*)d_in[1];
  const float* startv      = (const float*)d_in[2];
  const float* w_ih0 = (const float*)d_in[3];
  const float* w_hh0 = (const float*)d_in[4];
  const float* b_ih0 = (const float*)d_in[5];
  const float* b_hh0 = (const float*)d_in[6];
  const float* w_ih1 = (const float*)d_in[7];
  const float* w_hh1 = (const float*)d_in[8];
  const float* b_ih1 = (const float*)d_in[9];
  const float* b_hh1 = (const float*)d_in[10];
  const float* lin_w = (const float*)d_in[11];
  const float* lin_b = (const float*)d_in[12];
  const int*   ids   = (const int*)d_in[13];
  const int*   seq   = (const int*)d_in[14];
  float* out = (float*)d_out;

  // workspace layout
  float* xp  = (float*)d_ws;                       // M*G3
  float* ys0 = xp  + (size_t)M * G3;               // M*KD
  float* ys1 = ys0 + (size_t)M * KD;               // M*KD
  float* h0  = ys1 + (size_t)M * KD;               // B*KD
  unsigned short* ut_bf    = (unsigned short*)(h0 + (size_t)B * KD);
  unsigned short* start_bf = ut_bf    + (size_t)V * KD;
  unsigned short* wih0_bf  = start_bf + KD;
  unsigned short* wih1_bf  = wih0_bf  + (size_t)G3 * KD;
  unsigned short* linw_bf  = wih1_bf  + (size_t)G3 * KD;
  unsigned short* ys0_bf   = linw_bf  + (size_t)V * KD;
  unsigned short* ys1_bf   = ys0_bf   + (size_t)M * KD;

  init_h0<<<dim3(B), 256, 0, stream>>>(event_table, ids, h0);

  // fp32 -> bf16 conversions
  auto cvt = [&](const float* src, unsigned short* dst, long long n) {
    int blocks = (int)((n + 2047) / 2048);
    cvt_bf16<<<dim3(blocks), 256, 0, stream>>>(src, dst, n);
  };
  cvt(user_table, ut_bf,   (long long)V * KD);
  cvt(startv,     start_bf, KD);
  cvt(w_ih0,      wih0_bf, (long long)G3 * KD);
  cvt(w_ih1,      wih1_bf, (long long)G3 * KD);
  cvt(lin_w,      linw_bf, (long long)V * KD);

  // layer 0 input projection (gather from bf16 tables)
  gemm_bf16<1, 0><<<dim3((M + 127) / 128, G3 / 128), 256, 0, stream>>>(
      nullptr, wih0_bf, b_ih0, xp, G3, seq, start_bf, ut_bf);

  // layer 0 scan
  for (int t = 0; t < T; ++t) {
    const float* hin = (t == 0) ? h0 : ys0 + (size_t)(t - 1) * B * KD;
    gru_step<<<dim3(64, 3), 256, 0, stream>>>(
        xp + (size_t)t * B * G3, w_hh0, b_hh0, hin,
        ys0 + (size_t)t * B * KD, ys0_bf + (size_t)t * B * KD);
  }

  // layer 1 input projection
  gemm_bf16<0, 0><<<dim3((M + 127) / 128, G3 / 128), 256, 0, stream>>>(
      ys0_bf, wih1_bf, b_ih1, xp, G3, nullptr, nullptr, nullptr);

  // layer 1 scan
  for (int t = 0; t < T; ++t) {
    const float* hin = (t == 0) ? h0 : ys1 + (size_t)(t - 1) * B * KD;
    gru_step<<<dim3(64, 3), 256, 0, stream>>>(
        xp + (size_t)t * B * G3, w_hh1, b_hh1, hin,
        ys1 + (size_t)t * B * KD, ys1_bf + (size_t)t * B * KD);
  }

  // logits into d_out at [b][t][v]
  gemm_bf16<0, 1><<<dim3((M + 127) / 128, V / 128), 256, 0, stream>>>(
      ys1_bf, linw_bf, lin_b, out, V, nullptr, nullptr, nullptr);

  // masked softmax in place
  softmax_mask<<<dim3(T, B), 256, 0, stream>>>(out, seq);
}

// Round 6
// 6390.089 us; speedup vs baseline: 2.7988x; 2.3180x over previous
//
#include <hip/hip_runtime.h>
#include <cstddef>
#include <cstdint>

constexpr int B  = 48;
constexpr int L  = 192;
constexpr int T  = 193;    // L + 1
constexpr int KD = 1024;   // I == H
constexpr int G3 = 3072;   // 3*H
constexpr int V  = 8192;
constexpr int M  = T * B;  // 9264
constexpr int SB = 128;    // scan blocks: 8 h-channels each

typedef float f32x4 __attribute__((ext_vector_type(4)));
typedef short s16x8 __attribute__((ext_vector_type(8)));
typedef unsigned short u16x8 __attribute__((ext_vector_type(8)));

__device__ inline unsigned short f2bf(float f) {
  unsigned u = __builtin_bit_cast(unsigned, f);
  u += 0x7fffu + ((u >> 16) & 1u);   // round-to-nearest-even
  return (unsigned short)(u >> 16);
}
__device__ inline float bf2f(unsigned short h) {
  return __builtin_bit_cast(float, (unsigned)h << 16);
}

// ---------------------------------------------------------------------------
__global__ __launch_bounds__(256)
void init_h0(const float* __restrict__ et, const int* __restrict__ ids,
             float* __restrict__ h0f, unsigned short* __restrict__ h0hi,
             unsigned short* __restrict__ h0lo) {
  int b = blockIdx.x;
  int id = ids[b];
  float4 v = ((const float4*)(et + (size_t)id * KD))[threadIdx.x];
  ((float4*)(h0f + (size_t)b * KD))[threadIdx.x] = v;
  int base = b * KD + threadIdx.x * 4;
  float vv[4] = {v.x, v.y, v.z, v.w};
#pragma unroll
  for (int j = 0; j < 4; ++j) {
    unsigned short hi = f2bf(vv[j]);
    h0hi[base + j] = hi;
    h0lo[base + j] = f2bf(vv[j] - bf2f(hi));
  }
}

// fp32 -> bf16 (raw bits), 8 elems/thread
__global__ __launch_bounds__(256)
void cvt_bf16(const float* __restrict__ in, unsigned short* __restrict__ out,
              long long n) {
  long long i = ((long long)blockIdx.x * 256 + threadIdx.x) * 8;
  if (i + 8 > n) return;
  float4 v0 = *(const float4*)(in + i);
  float4 v1 = *(const float4*)(in + i + 4);
  u16x8 o;
  o[0] = f2bf(v0.x); o[1] = f2bf(v0.y); o[2] = f2bf(v0.z); o[3] = f2bf(v0.w);
  o[4] = f2bf(v1.x); o[5] = f2bf(v1.y); o[6] = f2bf(v1.z); o[7] = f2bf(v1.w);
  *(u16x8*)(out + i) = o;
}

// ---------------------------------------------------------------------------
// Repack w_hh [3*KD, KD] fp32 -> per-block split-bf16 [SB][32][KD] (hi, lo).
// Block bid owns channels [bid*8, bid*8+8); row r<24: gate g=r>>3, ch=r&7.
__global__ __launch_bounds__(256)
void repack_whh(const float* __restrict__ w_hh, unsigned short* __restrict__ hi,
                unsigned short* __restrict__ lo) {
  long long idx = ((long long)blockIdx.x * 256 + threadIdx.x) * 8;
  if (idx >= (long long)SB * 32 * KD) return;
  int k  = (int)(idx & (KD - 1));
  int rr = (int)(idx >> 10);
  int r = rr & 31, bid = rr >> 5;
  u16x8 h8 = (u16x8)0, l8 = (u16x8)0;
  if (r < 24) {
    int g = r >> 3, c = bid * 8 + (r & 7);
    const float* src = w_hh + ((size_t)(g * KD + c)) * KD + k;
    float4 v0 = *(const float4*)src, v1 = *(const float4*)(src + 4);
    float vv[8] = {v0.x, v0.y, v0.z, v0.w, v1.x, v1.y, v1.z, v1.w};
#pragma unroll
    for (int j = 0; j < 8; ++j) {
      unsigned short h = f2bf(vv[j]);
      h8[j] = h;
      l8[j] = f2bf(vv[j] - bf2f(h));
    }
  }
  *(u16x8*)(hi + idx) = h8;
  *(u16x8*)(lo + idx) = l8;
}

// ---------------------------------------------------------------------------
// bf16 MFMA GEMM (validated R2): C[m,n] = sum_k A[m,k]*W[n,k] + bias[n].
template<int GATHER, int OUTMODE>
__global__ __launch_bounds__(256)
void gemm_bf16(const unsigned short* __restrict__ A,
               const unsigned short* __restrict__ W,
               const float* __restrict__ bias, float* __restrict__ C, int Ndim,
               const int* __restrict__ seq,
               const unsigned short* __restrict__ start_bf,
               const unsigned short* __restrict__ table_bf) {
  __shared__ __align__(16) unsigned short a_s[128 * 32];
  __shared__ __align__(16) unsigned short b_s[128 * 32];
  const int tid  = threadIdx.x;
  const int lane = tid & 63;
  const int wave = tid >> 6;
  const int m0 = blockIdx.x * 128;
  const int n0 = blockIdx.y * 128;
  const int wr = wave >> 1, wc = wave & 1;

  f32x4 acc[4][4];
#pragma unroll
  for (int i = 0; i < 4; ++i)
#pragma unroll
    for (int j = 0; j < 4; ++j) acc[i][j] = (f32x4){0.f, 0.f, 0.f, 0.f};

  const int lrow = lane & 15;
  const int lkhi = lane >> 4;

  for (int kt = 0; kt < KD; kt += 32) {
    __syncthreads();
#pragma unroll
    for (int j = 0; j < 2; ++j) {
      int flat = tid * 16 + j * 4096;
      int row = flat >> 6;
      int cc = (flat >> 4) & 3;
      const unsigned short* src;
      if (GATHER) {
        int m = m0 + row; if (m >= M) m = 0;
        int t = m / B, b = m - t * B;
        const unsigned short* rowsrc =
            (t == 0) ? start_bf : (table_bf + (size_t)seq[b * L + t - 1] * KD);
        src = rowsrc + kt + cc * 8;
      } else {
        int m = m0 + row; if (m >= M) m = 0;
        src = A + (size_t)m * KD + kt + cc * 8;
      }
      *(int4*)((char*)a_s + flat) = *(const int4*)src;
    }
#pragma unroll
    for (int j = 0; j < 2; ++j) {
      int flat = tid * 16 + j * 4096;
      int row = flat >> 6;
      int cc = (flat >> 4) & 3;
      const unsigned short* src = W + (size_t)(n0 + row) * KD + kt + cc * 8;
      *(int4*)((char*)b_s + flat) = *(const int4*)src;
    }
    __syncthreads();

    s16x8 af[4], wf[4];
#pragma unroll
    for (int i = 0; i < 4; ++i) {
      int arow = wr * 64 + i * 16 + lrow;
      af[i] = *(const s16x8*)((const char*)a_s + arow * 64 + lkhi * 16);
      int brow = wc * 64 + i * 16 + lrow;
      wf[i] = *(const s16x8*)((const char*)b_s + brow * 64 + lkhi * 16);
    }
#pragma unroll
    for (int i = 0; i < 4; ++i)
#pragma unroll
      for (int j = 0; j < 4; ++j)
        acc[i][j] = __builtin_amdgcn_mfma_f32_16x16x32_bf16(af[i], wf[j],
                                                            acc[i][j], 0, 0, 0);
  }

#pragma unroll
  for (int i = 0; i < 4; ++i) {
#pragma unroll
    for (int r = 0; r < 4; ++r) {
      int m = m0 + wr * 64 + i * 16 + (lane >> 4) * 4 + r;
      if (m >= M) continue;
      size_t rowoff;
      if (OUTMODE == 0) {
        rowoff = (size_t)m * (size_t)Ndim;
      } else {
        int t = m / B, b = m - t * B;
        rowoff = ((size_t)b * T + t) * (size_t)Ndim;
      }
#pragma unroll
      for (int j = 0; j < 4; ++j) {
        int n = n0 + wc * 64 + j * 16 + (lane & 15);
        C[rowoff + n] = acc[i][j][r] + bias[n];
      }
    }
  }
}

// ---------------------------------------------------------------------------
// One GRU step via MFMA, per-step launch (no grid sync).
// Block bid owns 8 channels; reads packed W (hi/lo) + h_{t-1} (hi/lo bf16)
// straight from global (L2-warm), 3-term split MFMA, fp32 gates.
__global__ __launch_bounds__(256)
void gru_step_mfma(const float* __restrict__ xp_t,
                   const unsigned short* __restrict__ wpk_hi,
                   const unsigned short* __restrict__ wpk_lo,
                   const float* __restrict__ b_hh,
                   const unsigned short* __restrict__ Shi,
                   const unsigned short* __restrict__ Slo,
                   const float* __restrict__ h_old,
                   float* __restrict__ h_new,
                   unsigned short* __restrict__ y_hi,
                   unsigned short* __restrict__ y_lo) {
  __shared__ float cpart[4][48 * 33];   // [wave][batch*33 + wrow], padded
  const int tid = threadIdx.x, lane = tid & 63, wave = tid >> 6;
  const int bid = blockIdx.x, c0 = bid * 8;
  const int lrow = lane & 15, lkhi = lane >> 4;

  const unsigned short* wb_hi = wpk_hi + (size_t)bid * 32 * KD;
  const unsigned short* wb_lo = wpk_lo + (size_t)bid * 32 * KD;

  f32x4 acc[3][2];
#pragma unroll
  for (int i = 0; i < 3; ++i)
#pragma unroll
    for (int j = 0; j < 2; ++j) acc[i][j] = (f32x4){0.f, 0.f, 0.f, 0.f};

  // wave owns K range [wave*256, wave*256+256)
#pragma unroll
  for (int ks = 0; ks < 8; ++ks) {
    int k0 = wave * 256 + ks * 32 + lkhi * 8;
    s16x8 ah[3], al[3];
#pragma unroll
    for (int mt = 0; mt < 3; ++mt) {
      int b = mt * 16 + lrow;
      ah[mt] = *(const s16x8*)(Shi + (size_t)b * KD + k0);
      al[mt] = *(const s16x8*)(Slo + (size_t)b * KD + k0);
    }
    s16x8 bh[2], bl[2];
#pragma unroll
    for (int nt = 0; nt < 2; ++nt) {
      int r = nt * 16 + lrow;
      bh[nt] = *(const s16x8*)(wb_hi + (size_t)r * KD + k0);
      bl[nt] = *(const s16x8*)(wb_lo + (size_t)r * KD + k0);
    }
#pragma unroll
    for (int mt = 0; mt < 3; ++mt)
#pragma unroll
      for (int nt = 0; nt < 2; ++nt) {
        acc[mt][nt] = __builtin_amdgcn_mfma_f32_16x16x32_bf16(ah[mt], bh[nt], acc[mt][nt], 0, 0, 0);
        acc[mt][nt] = __builtin_amdgcn_mfma_f32_16x16x32_bf16(al[mt], bh[nt], acc[mt][nt], 0, 0, 0);
        acc[mt][nt] = __builtin_amdgcn_mfma_f32_16x16x32_bf16(ah[mt], bl[nt], acc[mt][nt], 0, 0, 0);
      }
  }

  // partials -> LDS: row = batch, col = w-row (0..31)
#pragma unroll
  for (int mt = 0; mt < 3; ++mt)
#pragma unroll
    for (int nt = 0; nt < 2; ++nt)
#pragma unroll
      for (int r = 0; r < 4; ++r) {
        int row = mt * 16 + (lane >> 4) * 4 + r;
        int col = nt * 16 + (lane & 15);
        cpart[wave][row * 33 + col] = acc[mt][nt][r];
      }
  __syncthreads();

  // gate + state update: 384 (b,c) pairs, each sums 4 wave-partials
  for (int p = tid; p < 384; p += 256) {
    int b = p >> 3, c = p & 7;
    float pr = 0.f, pz = 0.f, pn = 0.f;
#pragma unroll
    for (int w = 0; w < 4; ++w) {
      pr += cpart[w][b * 33 + c];
      pz += cpart[w][b * 33 + 8 + c];
      pn += cpart[w][b * 33 + 16 + c];
    }
    int gc = c0 + c;
    float hr = pr + b_hh[gc];
    float hz = pz + b_hh[KD + gc];
    float hn = pn + b_hh[2 * KD + gc];
    const float* xrow = xp_t + (size_t)b * G3;
    float r_ = 1.f / (1.f + expf(-(xrow[gc] + hr)));
    float z_ = 1.f / (1.f + expf(-(xrow[KD + gc] + hz)));
    float n_ = tanhf(xrow[2 * KD + gc] + r_ * hn);
    float hold = h_old[(size_t)b * KD + gc];
    float hnew = (1.f - z_) * n_ + z_ * hold;
    h_new[(size_t)b * KD + gc] = hnew;
    unsigned short hi = f2bf(hnew);
    y_hi[(size_t)b * KD + gc] = hi;
    y_lo[(size_t)b * KD + gc] = f2bf(hnew - bf2f(hi));
  }
}

// ---------------------------------------------------------------------------
__global__ __launch_bounds__(256)
void softmax_mask(float* __restrict__ out, const int* __restrict__ seq) {
  const int t = blockIdx.x, b = blockIdx.y;
  float* row = out + ((size_t)b * T + t) * V;
  __shared__ unsigned bits[V / 32];
  __shared__ float red[4];
  const int tid = threadIdx.x;
  const bool masked = (t < L - 1);
  if (masked) {
    bits[tid] = 0u;
    __syncthreads();
    int rem = L - t;
    if (tid < rem) {
      int id = seq[b * L + t + tid];
      atomicOr(&bits[id >> 5], 1u << (id & 31));
    }
  }
  __syncthreads();

  float4 x[8];
  float mx = -3.0e38f;
#pragma unroll
  for (int j = 0; j < 8; ++j) {
    float4 v = ((const float4*)row)[j * 256 + tid];
    if (masked) {
      int vb = (j * 256 + tid) * 4;
      unsigned wrd = bits[vb >> 5];
      int sh = vb & 31;
      if (!((wrd >> (sh + 0)) & 1u)) v.x = -1.0e30f;
      if (!((wrd >> (sh + 1)) & 1u)) v.y = -1.0e30f;
      if (!((wrd >> (sh + 2)) & 1u)) v.z = -1.0e30f;
      if (!((wrd >> (sh + 3)) & 1u)) v.w = -1.0e30f;
    }
    x[j] = v;
    mx = fmaxf(mx, fmaxf(fmaxf(v.x, v.y), fmaxf(v.z, v.w)));
  }
#pragma unroll
  for (int off = 32; off > 0; off >>= 1) mx = fmaxf(mx, __shfl_xor(mx, off));
  int wv = tid >> 6;
  if ((tid & 63) == 0) red[wv] = mx;
  __syncthreads();
  mx = fmaxf(fmaxf(red[0], red[1]), fmaxf(red[2], red[3]));

  float s = 0.f;
#pragma unroll
  for (int j = 0; j < 8; ++j) {
    x[j].x = expf(x[j].x - mx); x[j].y = expf(x[j].y - mx);
    x[j].z = expf(x[j].z - mx); x[j].w = expf(x[j].w - mx);
    s += x[j].x + x[j].y + x[j].z + x[j].w;
  }
#pragma unroll
  for (int off = 32; off > 0; off >>= 1) s += __shfl_xor(s, off);
  __syncthreads();
  if ((tid & 63) == 0) red[wv] = s;
  __syncthreads();
  s = red[0] + red[1] + red[2] + red[3];
  float inv = 1.f / s;
#pragma unroll
  for (int j = 0; j < 8; ++j) {
    float4 v = make_float4(x[j].x * inv, x[j].y * inv, x[j].z * inv, x[j].w * inv);
    ((float4*)row)[j * 256 + tid] = v;
  }
}

// ---------------------------------------------------------------------------
extern "C" void kernel_launch(void* const* d_in, const int* in_sizes, int n_in,
                              void* d_out, int out_size, void* d_ws, size_t ws_size,
                              hipStream_t stream) {
  const float* event_table = (const float*)d_in[0];
  const float* user_table  = (const float*)d_in[1];
  const float* startv      = (const float*)d_in[2];
  const float* w_ih0 = (const float*)d_in[3];
  const float* w_hh0 = (const float*)d_in[4];
  const float* b_ih0 = (const float*)d_in[5];
  const float* b_hh0 = (const float*)d_in[6];
  const float* w_ih1 = (const float*)d_in[7];
  const float* w_hh1 = (const float*)d_in[8];
  const float* b_ih1 = (const float*)d_in[9];
  const float* b_hh1 = (const float*)d_in[10];
  const float* lin_w = (const float*)d_in[11];
  const float* lin_b = (const float*)d_in[12];
  const int*   ids   = (const int*)d_in[13];
  const int*   seq   = (const int*)d_in[14];
  float* out = (float*)d_out;

  // workspace layout (~252 MB)
  float* xp   = (float*)d_ws;                           // M*G3 f32
  float* h0f  = xp + (size_t)M * G3;                    // B*KD
  float* hf32 = h0f + (size_t)B * KD;                   // B*KD
  unsigned short* ut_bf    = (unsigned short*)(hf32 + (size_t)B * KD);
  unsigned short* start_bf = ut_bf    + (size_t)V * KD;
  unsigned short* wih0_bf  = start_bf + KD;
  unsigned short* wih1_bf  = wih0_bf  + (size_t)G3 * KD;
  unsigned short* linw_bf  = wih1_bf  + (size_t)G3 * KD;
  unsigned short* ys0_bf   = linw_bf  + (size_t)V * KD;
  unsigned short* ys1_bf   = ys0_bf   + (size_t)M * KD;
  unsigned short* h0hi     = ys1_bf   + (size_t)M * KD;
  unsigned short* h0lo     = h0hi + (size_t)B * KD;
  unsigned short* lo0      = h0lo + (size_t)B * KD;
  unsigned short* lo1      = lo0  + (size_t)B * KD;
  unsigned short* wpk0_hi  = lo1  + (size_t)B * KD;
  unsigned short* wpk0_lo  = wpk0_hi + (size_t)SB * 32 * KD;
  unsigned short* wpk1_hi  = wpk0_lo + (size_t)SB * 32 * KD;
  unsigned short* wpk1_lo  = wpk1_hi + (size_t)SB * 32 * KD;

  init_h0<<<dim3(B), 256, 0, stream>>>(event_table, ids, h0f, h0hi, h0lo);

  auto cvt = [&](const float* src, unsigned short* dst, long long n) {
    int blocks = (int)((n + 2047) / 2048);
    cvt_bf16<<<dim3(blocks), 256, 0, stream>>>(src, dst, n);
  };
  cvt(user_table, ut_bf,    (long long)V * KD);
  cvt(startv,     start_bf, KD);
  cvt(w_ih0,      wih0_bf,  (long long)G3 * KD);
  cvt(w_ih1,      wih1_bf,  (long long)G3 * KD);
  cvt(lin_w,      linw_bf,  (long long)V * KD);

  repack_whh<<<dim3(SB * 32 * KD / 2048), 256, 0, stream>>>(w_hh0, wpk0_hi, wpk0_lo);
  repack_whh<<<dim3(SB * 32 * KD / 2048), 256, 0, stream>>>(w_hh1, wpk1_hi, wpk1_lo);

  // layer 0 input projection (gather from bf16 tables)
  gemm_bf16<1, 0><<<dim3((M + 127) / 128, G3 / 128), 256, 0, stream>>>(
      nullptr, wih0_bf, b_ih0, xp, G3, seq, start_bf, ut_bf);

  // layer 0 scan: per-step MFMA kernels
  for (int t = 0; t < T; ++t) {
    const unsigned short* Shi = (t == 0) ? h0hi : ys0_bf + (size_t)(t - 1) * B * KD;
    const unsigned short* Slo = (t == 0) ? h0lo : (((t - 1) & 1) ? lo1 : lo0);
    const float* hold = (t == 0) ? h0f : hf32;
    gru_step_mfma<<<dim3(SB), 256, 0, stream>>>(
        xp + (size_t)t * B * G3, wpk0_hi, wpk0_lo, b_hh0, Shi, Slo, hold, hf32,
        ys0_bf + (size_t)t * B * KD, (t & 1) ? lo1 : lo0);
  }

  // layer 1 input projection
  gemm_bf16<0, 0><<<dim3((M + 127) / 128, G3 / 128), 256, 0, stream>>>(
      ys0_bf, wih1_bf, b_ih1, xp, G3, nullptr, nullptr, nullptr);

  // layer 1 scan
  for (int t = 0; t < T; ++t) {
    const unsigned short* Shi = (t == 0) ? h0hi : ys1_bf + (size_t)(t - 1) * B * KD;
    const unsigned short* Slo = (t == 0) ? h0lo : (((t - 1) & 1) ? lo1 : lo0);
    const float* hold = (t == 0) ? h0f : hf32;
    gru_step_mfma<<<dim3(SB), 256, 0, stream>>>(
        xp + (size_t)t * B * G3, wpk1_hi, wpk1_lo, b_hh1, Shi, Slo, hold, hf32,
        ys1_bf + (size_t)t * B * KD, (t & 1) ? lo1 : lo0);
  }

  // logits into d_out at [b][t][v]
  gemm_bf16<0, 1><<<dim3((M + 127) / 128, V / 128), 256, 0, stream>>>(
      ys1_bf, linw_bf, lin_b, out, V, nullptr, nullptr, nullptr);

  // masked softmax in place
  softmax_mask<<<dim3(T, B), 256, 0, stream>>>(out, seq);
}

// Round 7
// 4076.236 us; speedup vs baseline: 4.3876x; 1.5676x over previous
//
#include <hip/hip_runtime.h>
#include <cstddef>
#include <cstdint>

constexpr int B  = 48;
constexpr int L  = 192;
constexpr int T  = 193;    // L + 1
constexpr int KD = 1024;   // I == H
constexpr int G3 = 3072;   // 3*H
constexpr int V  = 8192;
constexpr int M  = T * B;  // 9264
constexpr int SB = 128;    // scan blocks per layer: 8 h-channels each

typedef float f32x4 __attribute__((ext_vector_type(4)));
typedef short s16x8 __attribute__((ext_vector_type(8)));
typedef unsigned short u16x8 __attribute__((ext_vector_type(8)));

__device__ inline unsigned short f2bf(float f) {
  unsigned u = __builtin_bit_cast(unsigned, f);
  u += 0x7fffu + ((u >> 16) & 1u);   // round-to-nearest-even
  return (unsigned short)(u >> 16);
}
__device__ inline float bf2f(unsigned short h) {
  return __builtin_bit_cast(float, (unsigned)h << 16);
}

// ---------------------------------------------------------------------------
__global__ __launch_bounds__(256)
void init_h0(const float* __restrict__ et, const int* __restrict__ ids,
             float* __restrict__ h0f, unsigned short* __restrict__ h0hi,
             unsigned short* __restrict__ h0lo) {
  int b = blockIdx.x;
  int id = ids[b];
  float4 v = ((const float4*)(et + (size_t)id * KD))[threadIdx.x];
  ((float4*)(h0f + (size_t)b * KD))[threadIdx.x] = v;
  int base = b * KD + threadIdx.x * 4;
  float vv[4] = {v.x, v.y, v.z, v.w};
#pragma unroll
  for (int j = 0; j < 4; ++j) {
    unsigned short hi = f2bf(vv[j]);
    h0hi[base + j] = hi;
    h0lo[base + j] = f2bf(vv[j] - bf2f(hi));
  }
}

// fp32 -> bf16 (raw bits), 8 elems/thread
__global__ __launch_bounds__(256)
void cvt_bf16(const float* __restrict__ in, unsigned short* __restrict__ out,
              long long n) {
  long long i = ((long long)blockIdx.x * 256 + threadIdx.x) * 8;
  if (i + 8 > n) return;
  float4 v0 = *(const float4*)(in + i);
  float4 v1 = *(const float4*)(in + i + 4);
  u16x8 o;
  o[0] = f2bf(v0.x); o[1] = f2bf(v0.y); o[2] = f2bf(v0.z); o[3] = f2bf(v0.w);
  o[4] = f2bf(v1.x); o[5] = f2bf(v1.y); o[6] = f2bf(v1.z); o[7] = f2bf(v1.w);
  *(u16x8*)(out + i) = o;
}

// ---------------------------------------------------------------------------
// Repack [3*KD, KD] fp32 weights -> per-block split-bf16 [SB][32][KD] (hi,lo).
__global__ __launch_bounds__(256)
void repack_whh(const float* __restrict__ w_hh, unsigned short* __restrict__ hi,
                unsigned short* __restrict__ lo) {
  long long idx = ((long long)blockIdx.x * 256 + threadIdx.x) * 8;
  if (idx >= (long long)SB * 32 * KD) return;
  int k  = (int)(idx & (KD - 1));
  int rr = (int)(idx >> 10);
  int r = rr & 31, bid = rr >> 5;
  u16x8 h8 = (u16x8)0, l8 = (u16x8)0;
  if (r < 24) {
    int g = r >> 3, c = bid * 8 + (r & 7);
    const float* src = w_hh + ((size_t)(g * KD + c)) * KD + k;
    float4 v0 = *(const float4*)src, v1 = *(const float4*)(src + 4);
    float vv[8] = {v0.x, v0.y, v0.z, v0.w, v1.x, v1.y, v1.z, v1.w};
#pragma unroll
    for (int j = 0; j < 8; ++j) {
      unsigned short h = f2bf(vv[j]);
      h8[j] = h;
      l8[j] = f2bf(vv[j] - bf2f(h));
    }
  }
  *(u16x8*)(hi + idx) = h8;
  *(u16x8*)(lo + idx) = l8;
}

// Same packing, single bf16 (for w_ih1 used by the on-the-fly x-projection).
__global__ __launch_bounds__(256)
void repack_w_single(const float* __restrict__ w, unsigned short* __restrict__ pk) {
  long long idx = ((long long)blockIdx.x * 256 + threadIdx.x) * 8;
  if (idx >= (long long)SB * 32 * KD) return;
  int k  = (int)(idx & (KD - 1));
  int rr = (int)(idx >> 10);
  int r = rr & 31, bid = rr >> 5;
  u16x8 h8 = (u16x8)0;
  if (r < 24) {
    int g = r >> 3, c = bid * 8 + (r & 7);
    const float* src = w + ((size_t)(g * KD + c)) * KD + k;
    float4 v0 = *(const float4*)src, v1 = *(const float4*)(src + 4);
    float vv[8] = {v0.x, v0.y, v0.z, v0.w, v1.x, v1.y, v1.z, v1.w};
#pragma unroll
    for (int j = 0; j < 8; ++j) h8[j] = f2bf(vv[j]);
  }
  *(u16x8*)(pk + idx) = h8;
}

// ---------------------------------------------------------------------------
// bf16 MFMA GEMM (validated R2): C[m,n] = sum_k A[m,k]*W[n,k] + bias[n].
template<int GATHER, int OUTMODE>
__global__ __launch_bounds__(256)
void gemm_bf16(const unsigned short* __restrict__ A,
               const unsigned short* __restrict__ W,
               const float* __restrict__ bias, float* __restrict__ C, int Ndim,
               const int* __restrict__ seq,
               const unsigned short* __restrict__ start_bf,
               const unsigned short* __restrict__ table_bf) {
  __shared__ __align__(16) unsigned short a_s[128 * 32];
  __shared__ __align__(16) unsigned short b_s[128 * 32];
  const int tid  = threadIdx.x;
  const int lane = tid & 63;
  const int wave = tid >> 6;
  const int m0 = blockIdx.x * 128;
  const int n0 = blockIdx.y * 128;
  const int wr = wave >> 1, wc = wave & 1;

  f32x4 acc[4][4];
#pragma unroll
  for (int i = 0; i < 4; ++i)
#pragma unroll
    for (int j = 0; j < 4; ++j) acc[i][j] = (f32x4){0.f, 0.f, 0.f, 0.f};

  const int lrow = lane & 15;
  const int lkhi = lane >> 4;

  for (int kt = 0; kt < KD; kt += 32) {
    __syncthreads();
#pragma unroll
    for (int j = 0; j < 2; ++j) {
      int flat = tid * 16 + j * 4096;
      int row = flat >> 6;
      int cc = (flat >> 4) & 3;
      const unsigned short* src;
      if (GATHER) {
        int m = m0 + row; if (m >= M) m = 0;
        int t = m / B, b = m - t * B;
        const unsigned short* rowsrc =
            (t == 0) ? start_bf : (table_bf + (size_t)seq[b * L + t - 1] * KD);
        src = rowsrc + kt + cc * 8;
      } else {
        int m = m0 + row; if (m >= M) m = 0;
        src = A + (size_t)m * KD + kt + cc * 8;
      }
      *(int4*)((char*)a_s + flat) = *(const int4*)src;
    }
#pragma unroll
    for (int j = 0; j < 2; ++j) {
      int flat = tid * 16 + j * 4096;
      int row = flat >> 6;
      int cc = (flat >> 4) & 3;
      const unsigned short* src = W + (size_t)(n0 + row) * KD + kt + cc * 8;
      *(int4*)((char*)b_s + flat) = *(const int4*)src;
    }
    __syncthreads();

    s16x8 af[4], wf[4];
#pragma unroll
    for (int i = 0; i < 4; ++i) {
      int arow = wr * 64 + i * 16 + lrow;
      af[i] = *(const s16x8*)((const char*)a_s + arow * 64 + lkhi * 16);
      int brow = wc * 64 + i * 16 + lrow;
      wf[i] = *(const s16x8*)((const char*)b_s + brow * 64 + lkhi * 16);
    }
#pragma unroll
    for (int i = 0; i < 4; ++i)
#pragma unroll
      for (int j = 0; j < 4; ++j)
        acc[i][j] = __builtin_amdgcn_mfma_f32_16x16x32_bf16(af[i], wf[j],
                                                            acc[i][j], 0, 0, 0);
  }

#pragma unroll
  for (int i = 0; i < 4; ++i) {
#pragma unroll
    for (int r = 0; r < 4; ++r) {
      int m = m0 + wr * 64 + i * 16 + (lane >> 4) * 4 + r;
      if (m >= M) continue;
      size_t rowoff;
      if (OUTMODE == 0) {
        rowoff = (size_t)m * (size_t)Ndim;
      } else {
        int t = m / B, b = m - t * B;
        rowoff = ((size_t)b * T + t) * (size_t)Ndim;
      }
#pragma unroll
      for (int j = 0; j < 4; ++j) {
        int n = n0 + wc * 64 + j * 16 + (lane & 15);
        C[rowoff + n] = acc[i][j][r] + bias[n];
      }
    }
  }
}

// ---------------------------------------------------------------------------
// Core of one GRU step for one block's 8 channels.
// HASX=0: x-projection precomputed in xp_t (fp32 [B,3H]).
// HASX=1: x-projection computed on the fly from Xhi (bf16 [B,KD]) and packed
//         w_ih (single bf16), bias b_ih added in the tail.
template<int HASX>
__device__ __forceinline__ void gru_core(
    int c0, int tid,
    const float* __restrict__ xp_t, const unsigned short* __restrict__ Xhi,
    const unsigned short* __restrict__ wih_pk, const float* __restrict__ b_ih,
    const unsigned short* __restrict__ wb_hi, const unsigned short* __restrict__ wb_lo,
    const float* __restrict__ b_hh,
    const unsigned short* __restrict__ Shi, const unsigned short* __restrict__ Slo,
    const float* __restrict__ h_old, float* __restrict__ h_new,
    unsigned short* __restrict__ y_hi, unsigned short* __restrict__ y_lo,
    float (*cp_h)[48 * 33], float (*cp_x)[48 * 33]) {
  const int lane = tid & 63, wave = tid >> 6;
  const int lrow = lane & 15, lkhi = lane >> 4;

  f32x4 acc_h[3][2], acc_x[3][2];
#pragma unroll
  for (int i = 0; i < 3; ++i)
#pragma unroll
    for (int j = 0; j < 2; ++j) {
      acc_h[i][j] = (f32x4){0.f, 0.f, 0.f, 0.f};
      acc_x[i][j] = (f32x4){0.f, 0.f, 0.f, 0.f};
    }

  // wave owns K range [wave*256, wave*256+256)
#pragma unroll
  for (int ks = 0; ks < 8; ++ks) {
    int k0 = wave * 256 + ks * 32 + lkhi * 8;
    s16x8 ah[3], al[3], xh[3];
#pragma unroll
    for (int mt = 0; mt < 3; ++mt) {
      int b = mt * 16 + lrow;
      ah[mt] = *(const s16x8*)(Shi + (size_t)b * KD + k0);
      al[mt] = *(const s16x8*)(Slo + (size_t)b * KD + k0);
      if (HASX) xh[mt] = *(const s16x8*)(Xhi + (size_t)b * KD + k0);
    }
    s16x8 bh[2], bl[2], wx[2];
#pragma unroll
    for (int nt = 0; nt < 2; ++nt) {
      int r = nt * 16 + lrow;
      bh[nt] = *(const s16x8*)(wb_hi + (size_t)r * KD + k0);
      bl[nt] = *(const s16x8*)(wb_lo + (size_t)r * KD + k0);
      if (HASX) wx[nt] = *(const s16x8*)(wih_pk + (size_t)r * KD + k0);
    }
#pragma unroll
    for (int mt = 0; mt < 3; ++mt)
#pragma unroll
      for (int nt = 0; nt < 2; ++nt) {
        acc_h[mt][nt] = __builtin_amdgcn_mfma_f32_16x16x32_bf16(ah[mt], bh[nt], acc_h[mt][nt], 0, 0, 0);
        acc_h[mt][nt] = __builtin_amdgcn_mfma_f32_16x16x32_bf16(al[mt], bh[nt], acc_h[mt][nt], 0, 0, 0);
        acc_h[mt][nt] = __builtin_amdgcn_mfma_f32_16x16x32_bf16(ah[mt], bl[nt], acc_h[mt][nt], 0, 0, 0);
        if (HASX)
          acc_x[mt][nt] = __builtin_amdgcn_mfma_f32_16x16x32_bf16(xh[mt], wx[nt], acc_x[mt][nt], 0, 0, 0);
      }
  }

  // partials -> LDS: row = batch, col = w-row (0..31)
#pragma unroll
  for (int mt = 0; mt < 3; ++mt)
#pragma unroll
    for (int nt = 0; nt < 2; ++nt)
#pragma unroll
      for (int r = 0; r < 4; ++r) {
        int row = mt * 16 + (lane >> 4) * 4 + r;
        int col = nt * 16 + (lane & 15);
        cp_h[wave][row * 33 + col] = acc_h[mt][nt][r];
        if (HASX) cp_x[wave][row * 33 + col] = acc_x[mt][nt][r];
      }
  __syncthreads();

  // gate + state update: 384 (b,c) pairs, each sums 4 wave-partials
  for (int p = tid; p < 384; p += 256) {
    int b = p >> 3, c = p & 7;
    float pr = 0.f, pz = 0.f, pn = 0.f;
    float xr, xz, xn;
#pragma unroll
    for (int w = 0; w < 4; ++w) {
      pr += cp_h[w][b * 33 + c];
      pz += cp_h[w][b * 33 + 8 + c];
      pn += cp_h[w][b * 33 + 16 + c];
    }
    int gc = c0 + c;
    if (HASX) {
      float qr = 0.f, qz = 0.f, qn = 0.f;
#pragma unroll
      for (int w = 0; w < 4; ++w) {
        qr += cp_x[w][b * 33 + c];
        qz += cp_x[w][b * 33 + 8 + c];
        qn += cp_x[w][b * 33 + 16 + c];
      }
      xr = qr + b_ih[gc];
      xz = qz + b_ih[KD + gc];
      xn = qn + b_ih[2 * KD + gc];
    } else {
      const float* xrow = xp_t + (size_t)b * G3;
      xr = xrow[gc]; xz = xrow[KD + gc]; xn = xrow[2 * KD + gc];
    }
    float hr = pr + b_hh[gc];
    float hz = pz + b_hh[KD + gc];
    float hn = pn + b_hh[2 * KD + gc];
    float r_ = 1.f / (1.f + expf(-(xr + hr)));
    float z_ = 1.f / (1.f + expf(-(xz + hz)));
    float n_ = tanhf(xn + r_ * hn);
    float hold = h_old[(size_t)b * KD + gc];
    float hnew = (1.f - z_) * n_ + z_ * hold;
    h_new[(size_t)b * KD + gc] = hnew;
    unsigned short hi = f2bf(hnew);
    y_hi[(size_t)b * KD + gc] = hi;
    y_lo[(size_t)b * KD + gc] = f2bf(hnew - bf2f(hi));
  }
}

// ---------------------------------------------------------------------------
// Pipelined fused step: blocks [0,SB) run layer0 step t; blocks [SB,2SB) run
// layer1 step t-1 (x-projection on the fly from ys0_bf[t-1]).
__global__ __launch_bounds__(256)
void gru_pipe(int t,
              const float* __restrict__ xp0,
              const unsigned short* __restrict__ wpk0_hi,
              const unsigned short* __restrict__ wpk0_lo,
              const float* __restrict__ b_hh0,
              const unsigned short* __restrict__ wpk1_hi,
              const unsigned short* __restrict__ wpk1_lo,
              const unsigned short* __restrict__ wih1pk,
              const float* __restrict__ b_ih1,
              const float* __restrict__ b_hh1,
              const unsigned short* __restrict__ h0hi,
              const unsigned short* __restrict__ h0lo,
              const float* __restrict__ h0f,
              unsigned short* __restrict__ ys0_bf,
              unsigned short* __restrict__ lo0a, unsigned short* __restrict__ lo0b,
              float* __restrict__ h0f32,
              unsigned short* __restrict__ ys1_bf,
              unsigned short* __restrict__ lo1a, unsigned short* __restrict__ lo1b,
              float* __restrict__ h1f32) {
  __shared__ float cp_h[4][48 * 33];
  __shared__ float cp_x[4][48 * 33];
  const int tid = threadIdx.x;
  const bool is1 = blockIdx.x >= SB;
  const int bid = is1 ? (int)blockIdx.x - SB : (int)blockIdx.x;
  const int c0 = bid * 8;

  if (!is1) {
    if (t >= T) return;
    const unsigned short* Shi = (t == 0) ? h0hi : ys0_bf + (size_t)(t - 1) * B * KD;
    const unsigned short* Slo = (t == 0) ? h0lo : (((t - 1) & 1) ? lo0b : lo0a);
    const float* hold = (t == 0) ? h0f : h0f32;
    gru_core<0>(c0, tid, xp0 + (size_t)t * B * G3, nullptr, nullptr, nullptr,
                wpk0_hi + (size_t)bid * 32 * KD, wpk0_lo + (size_t)bid * 32 * KD,
                b_hh0, Shi, Slo, hold, h0f32,
                ys0_bf + (size_t)t * B * KD, (t & 1) ? lo0b : lo0a,
                cp_h, cp_x);
  } else {
    int s = t - 1;
    if (s < 0) return;
    const unsigned short* Shi = (s == 0) ? h0hi : ys1_bf + (size_t)(s - 1) * B * KD;
    const unsigned short* Slo = (s == 0) ? h0lo : (((s - 1) & 1) ? lo1b : lo1a);
    const float* hold = (s == 0) ? h0f : h1f32;
    gru_core<1>(c0, tid, nullptr, ys0_bf + (size_t)s * B * KD,
                wih1pk + (size_t)bid * 32 * KD, b_ih1,
                wpk1_hi + (size_t)bid * 32 * KD, wpk1_lo + (size_t)bid * 32 * KD,
                b_hh1, Shi, Slo, hold, h1f32,
                ys1_bf + (size_t)s * B * KD, (s & 1) ? lo1b : lo1a,
                cp_h, cp_x);
  }
}

// ---------------------------------------------------------------------------
__global__ __launch_bounds__(256)
void softmax_mask(float* __restrict__ out, const int* __restrict__ seq) {
  const int t = blockIdx.x, b = blockIdx.y;
  float* row = out + ((size_t)b * T + t) * V;
  __shared__ unsigned bits[V / 32];
  __shared__ float red[4];
  const int tid = threadIdx.x;
  const bool masked = (t < L - 1);
  if (masked) {
    bits[tid] = 0u;
    __syncthreads();
    int rem = L - t;
    if (tid < rem) {
      int id = seq[b * L + t + tid];
      atomicOr(&bits[id >> 5], 1u << (id & 31));
    }
  }
  __syncthreads();

  float4 x[8];
  float mx = -3.0e38f;
#pragma unroll
  for (int j = 0; j < 8; ++j) {
    float4 v = ((const float4*)row)[j * 256 + tid];
    if (masked) {
      int vb = (j * 256 + tid) * 4;
      unsigned wrd = bits[vb >> 5];
      int sh = vb & 31;
      if (!((wrd >> (sh + 0)) & 1u)) v.x = -1.0e30f;
      if (!((wrd >> (sh + 1)) & 1u)) v.y = -1.0e30f;
      if (!((wrd >> (sh + 2)) & 1u)) v.z = -1.0e30f;
      if (!((wrd >> (sh + 3)) & 1u)) v.w = -1.0e30f;
    }
    x[j] = v;
    mx = fmaxf(mx, fmaxf(fmaxf(v.x, v.y), fmaxf(v.z, v.w)));
  }
#pragma unroll
  for (int off = 32; off > 0; off >>= 1) mx = fmaxf(mx, __shfl_xor(mx, off));
  int wv = tid >> 6;
  if ((tid & 63) == 0) red[wv] = mx;
  __syncthreads();
  mx = fmaxf(fmaxf(red[0], red[1]), fmaxf(red[2], red[3]));

  float s = 0.f;
#pragma unroll
  for (int j = 0; j < 8; ++j) {
    x[j].x = expf(x[j].x - mx); x[j].y = expf(x[j].y - mx);
    x[j].z = expf(x[j].z - mx); x[j].w = expf(x[j].w - mx);
    s += x[j].x + x[j].y + x[j].z + x[j].w;
  }
#pragma unroll
  for (int off = 32; off > 0; off >>= 1) s += __shfl_xor(s, off);
  __syncthreads();
  if ((tid & 63) == 0) red[wv] = s;
  __syncthreads();
  s = red[0] + red[1] + red[2] + red[3];
  float inv = 1.f / s;
#pragma unroll
  for (int j = 0; j < 8; ++j) {
    float4 v = make_float4(x[j].x * inv, x[j].y * inv, x[j].z * inv, x[j].w * inv);
    ((float4*)row)[j * 256 + tid] = v;
  }
}

// ---------------------------------------------------------------------------
extern "C" void kernel_launch(void* const* d_in, const int* in_sizes, int n_in,
                              void* d_out, int out_size, void* d_ws, size_t ws_size,
                              hipStream_t stream) {
  const float* event_table = (const float*)d_in[0];
  const float* user_table  = (const float*)d_in[1];
  const float* startv      = (const float*)d_in[2];
  const float* w_ih0 = (const float*)d_in[3];
  const float* w_hh0 = (const float*)d_in[4];
  const float* b_ih0 = (const float*)d_in[5];
  const float* b_hh0 = (const float*)d_in[6];
  const float* w_ih1 = (const float*)d_in[7];
  const float* w_hh1 = (const float*)d_in[8];
  const float* b_ih1 = (const float*)d_in[9];
  const float* b_hh1 = (const float*)d_in[10];
  const float* lin_w = (const float*)d_in[11];
  const float* lin_b = (const float*)d_in[12];
  const int*   ids   = (const int*)d_in[13];
  const int*   seq   = (const int*)d_in[14];
  float* out = (float*)d_out;

  // workspace layout (~235 MB)
  float* xp0  = (float*)d_ws;                           // M*G3 f32
  float* h0f  = xp0 + (size_t)M * G3;                   // B*KD
  float* h0f32 = h0f + (size_t)B * KD;                  // B*KD (layer0 state)
  float* h1f32 = h0f32 + (size_t)B * KD;                // B*KD (layer1 state)
  unsigned short* ut_bf    = (unsigned short*)(h1f32 + (size_t)B * KD);
  unsigned short* start_bf = ut_bf    + (size_t)V * KD;
  unsigned short* wih0_bf  = start_bf + KD;
  unsigned short* linw_bf  = wih0_bf  + (size_t)G3 * KD;
  unsigned short* ys0_bf   = linw_bf  + (size_t)V * KD;
  unsigned short* ys1_bf   = ys0_bf   + (size_t)M * KD;
  unsigned short* h0hi     = ys1_bf   + (size_t)M * KD;
  unsigned short* h0lo     = h0hi + (size_t)B * KD;
  unsigned short* lo0a     = h0lo + (size_t)B * KD;
  unsigned short* lo0b     = lo0a + (size_t)B * KD;
  unsigned short* lo1a     = lo0b + (size_t)B * KD;
  unsigned short* lo1b     = lo1a + (size_t)B * KD;
  unsigned short* wpk0_hi  = lo1b + (size_t)B * KD;
  unsigned short* wpk0_lo  = wpk0_hi + (size_t)SB * 32 * KD;
  unsigned short* wpk1_hi  = wpk0_lo + (size_t)SB * 32 * KD;
  unsigned short* wpk1_lo  = wpk1_hi + (size_t)SB * 32 * KD;
  unsigned short* wih1pk   = wpk1_lo + (size_t)SB * 32 * KD;

  init_h0<<<dim3(B), 256, 0, stream>>>(event_table, ids, h0f, h0hi, h0lo);

  auto cvt = [&](const float* src, unsigned short* dst, long long n) {
    int blocks = (int)((n + 2047) / 2048);
    cvt_bf16<<<dim3(blocks), 256, 0, stream>>>(src, dst, n);
  };
  cvt(user_table, ut_bf,    (long long)V * KD);
  cvt(startv,     start_bf, KD);
  cvt(w_ih0,      wih0_bf,  (long long)G3 * KD);
  cvt(lin_w,      linw_bf,  (long long)V * KD);

  repack_whh<<<dim3(SB * 32 * KD / 2048), 256, 0, stream>>>(w_hh0, wpk0_hi, wpk0_lo);
  repack_whh<<<dim3(SB * 32 * KD / 2048), 256, 0, stream>>>(w_hh1, wpk1_hi, wpk1_lo);
  repack_w_single<<<dim3(SB * 32 * KD / 2048), 256, 0, stream>>>(w_ih1, wih1pk);

  // layer 0 input projection (gather from bf16 tables)
  gemm_bf16<1, 0><<<dim3((M + 127) / 128, G3 / 128), 256, 0, stream>>>(
      nullptr, wih0_bf, b_ih0, xp0, G3, seq, start_bf, ut_bf);

  // pipelined two-layer scan: T+1 launches of 2*SB blocks
  for (int t = 0; t <= T; ++t) {
    gru_pipe<<<dim3(2 * SB), 256, 0, stream>>>(
        t, xp0, wpk0_hi, wpk0_lo, b_hh0, wpk1_hi, wpk1_lo, wih1pk, b_ih1, b_hh1,
        h0hi, h0lo, h0f, ys0_bf, lo0a, lo0b, h0f32, ys1_bf, lo1a, lo1b, h1f32);
  }

  // logits into d_out at [b][t][v]
  gemm_bf16<0, 1><<<dim3((M + 127) / 128, V / 128), 256, 0, stream>>>(
      ys1_bf, linw_bf, lin_b, out, V, nullptr, nullptr, nullptr);

  // masked softmax in place
  softmax_mask<<<dim3(T, B), 256, 0, stream>>>(out, seq);
}